// Round 1
// baseline (246.908 us; speedup 1.0000x reference)
//
#include <hip/hip_runtime.h>

// ARModel: out[b,t,n,0] = (t==0) ? 0 : x[b,t-1,n,0]*w[0,0,0] + bias[0]
// B=64, T=288, N=2000, C=1, p=1, out_dim=1 (fp32 in / fp32 out).
// Flat: out[i] = (i % (T*N) < N) ? 0 : x[i-N]*w + b
// Memory-bound: ~295 MB total traffic -> ~50 us floor at 6.3 TB/s.

static constexpr int  kN4   = 500;       // N/4 float4 per t-row
static constexpr int  kTN4  = 144000;    // T*N/4 float4 per batch
static constexpr long kTot4 = 9216000L;  // B*T*N/4 total float4

__global__ __launch_bounds__(256) void ARModel_88880053223563_kernel(
    const float4* __restrict__ x,
    const float*  __restrict__ w,
    const float*  __restrict__ bias,
    float4*       __restrict__ out)
{
    long i = (long)blockIdx.x * blockDim.x + threadIdx.x;
    if (i >= kTot4) return;

    // Uniform scalar loads (broadcast, cached)
    const float wv = w[0];
    const float bv = bias[0];

    // Position within the batch; a float4 group never straddles a t-row
    // because N and T*N are multiples of 4.
    const int rem = (int)(i % kTN4);

    float4 v;
    if (rem < kN4) {
        // t == 0 row: reference leaves it zero; d_out is poisoned, so write 0.
        v = make_float4(0.f, 0.f, 0.f, 0.f);
    } else {
        const float4 xi = x[i - kN4];
        v = make_float4(fmaf(xi.x, wv, bv),
                        fmaf(xi.y, wv, bv),
                        fmaf(xi.z, wv, bv),
                        fmaf(xi.w, wv, bv));
    }
    out[i] = v;
}

extern "C" void kernel_launch(void* const* d_in, const int* in_sizes, int n_in,
                              void* d_out, int out_size, void* d_ws, size_t ws_size,
                              hipStream_t stream) {
    const float4* x    = (const float4*)d_in[0];
    const float*  w    = (const float*)d_in[1];
    const float*  bias = (const float*)d_in[2];
    float4*       out  = (float4*)d_out;

    // kTot4 = 9,216,000 = 36000 * 256 exactly — no tail.
    const int block = 256;
    const int grid  = (int)(kTot4 / block);
    ARModel_88880053223563_kernel<<<grid, block, 0, stream>>>(x, w, bias, out);
}

// Round 2
// 241.657 us; speedup vs baseline: 1.0217x; 1.0217x over previous
//
#include <hip/hip_runtime.h>

// ARModel: out[b,t,n,0] = (t==0) ? 0 : x[b,t-1,n,0]*w[0,0,0] + bias[0]
// B=64, T=288, N=2000, C=1, p=1, out_dim=1 (fp32 in / fp32 out).
// Memory-bound: 147 MB read + 147 MB write -> ~44-55 us floor at ~6.7 TB/s
// (ceiling demonstrated by the harness's own fillBuffer at 6.70 TB/s).
//
// v2 changes vs v1:
//  - 2D grid (y = batch) removes the 64-bit modulo.
//  - nontemporal load/store: both streams are touch-once, bypass L2.

typedef float f4 __attribute__((ext_vector_type(4)));

static constexpr int kN4  = 500;     // N/4 float4 per t-row
static constexpr int kTN4 = 144000;  // T*N/4 float4 per batch

__global__ __launch_bounds__(256) void ARModel_88880053223563_kernel(
    const f4* __restrict__ x,
    const float* __restrict__ w,
    const float* __restrict__ bias,
    f4* __restrict__ out)
{
    const int rem = blockIdx.x * 256 + threadIdx.x;  // float4 index within batch
    if (rem >= kTN4) return;
    const long i = (long)blockIdx.y * kTN4 + rem;

    f4 v;
    if (rem < kN4) {
        // t == 0 row stays zero (d_out is poisoned each call, must write).
        v = (f4){0.f, 0.f, 0.f, 0.f};
    } else {
        const f4 xi = __builtin_nontemporal_load(&x[i - kN4]);
        const float wv = w[0];   // uniform scalar loads (s_load broadcast)
        const float bv = bias[0];
        v.x = fmaf(xi.x, wv, bv);
        v.y = fmaf(xi.y, wv, bv);
        v.z = fmaf(xi.z, wv, bv);
        v.w = fmaf(xi.w, wv, bv);
    }
    __builtin_nontemporal_store(v, &out[i]);
}

extern "C" void kernel_launch(void* const* d_in, const int* in_sizes, int n_in,
                              void* d_out, int out_size, void* d_ws, size_t ws_size,
                              hipStream_t stream) {
    const f4*    x    = (const f4*)d_in[0];
    const float* w    = (const float*)d_in[1];
    const float* bias = (const float*)d_in[2];
    f4*          out  = (f4*)d_out;

    // 144000 float4 per batch -> 563 blocks of 256 (tail guard), 64 batches.
    dim3 grid((kTN4 + 255) / 256, 64);
    ARModel_88880053223563_kernel<<<grid, dim3(256), 0, stream>>>(x, w, bias, out);
}